// Round 1
// baseline (76.535 us; speedup 1.0000x reference)
//
#include <hip/hip_runtime.h>

// loss = (N*S - ||colsum||^2) / (sqrt(max_i sq_i) * N*(N-1)/2)
// where S = sum of all x^2, colsum[d] = sum_i x[i][d], sq_i = row squared norm.
// Derivation: sum_{i<j} (sq_i + sq_j - 2 x_i.x_j) = N*S - ||colsum||^2.
//
// 2-stage:
//   pass1 (256 blocks x 1024 thr): per-block colsum[512]/S/max partials.
//         16 waves/block (4/SIMD) -> short per-wave serial chain (2 rows each).
//         LDS colsum padded c -> c + (c>>3): atomic addr = lane*9+k, 9 coprime
//         32 => ~2-way banks instead of 16-way at stride 8.
//         Block 0 also zeroes the 4 finisher slots (counter re-zeroed every
//         launch => graph-replay safe; ws is poisoned between iterations).
//   pass2 (64 blocks x 256 thr): block j reduces cols [8j,8j+8) over the 256
//         partials -> q partial; also 4-wide slice of S/max partials; then
//         device-scope atomic accumulate + last-block-done finisher emits the
//         scalar. (Merges old pass2a+pass2b: one fewer dispatch.)

#define NROWS 8192
#define NCOLS 512
#define NB1   256                 // pass1 block count
#define NB2   64                  // pass2 block count
#define PS    (NB1 * NCOLS)       // ws: S partials [NB1]
#define PM    (PS + NB1)          // ws: max partials [NB1]
#define PACC  (PM + NB1)          // ws: q_acc, s_acc, m_acc(uint), counter(uint)

__global__ __launch_bounds__(1024) void ndl_pass1(const float* __restrict__ x,
                                                  float* __restrict__ ws) {
    __shared__ float colsum[NCOLS + NCOLS / 8];   // 576 floats, padded layout
    __shared__ float s_part[16];
    __shared__ float m_part[16];
    const int t    = threadIdx.x;
    const int lane = t & 63;
    const int wave = t >> 6;

    if (t < NCOLS + NCOLS / 8) colsum[t] = 0.f;
    // finisher slots for pass2 (zeroed every launch -> graph-replay safe)
    if (blockIdx.x == 0 && t < 4) ws[PACC + t] = 0.f;
    __syncthreads();

    // wave handles 2 consecutive rows; lane l covers columns 8l..8l+7
    const int row0 = blockIdx.x * 32 + wave * 2;
    const float4* xv = (const float4*)x;  // row stride = 128 float4

    float4 a0 = xv[(size_t)row0 * 128 + lane * 2];
    float4 b0 = xv[(size_t)row0 * 128 + lane * 2 + 1];
    float4 a1 = xv[(size_t)(row0 + 1) * 128 + lane * 2];
    float4 b1 = xv[(size_t)(row0 + 1) * 128 + lane * 2 + 1];

    float col[8];
    col[0] = a0.x + a1.x; col[1] = a0.y + a1.y;
    col[2] = a0.z + a1.z; col[3] = a0.w + a1.w;
    col[4] = b0.x + b1.x; col[5] = b0.y + b1.y;
    col[6] = b0.z + b1.z; col[7] = b0.w + b1.w;

    float r0 = a0.x*a0.x + a0.y*a0.y + a0.z*a0.z + a0.w*a0.w
             + b0.x*b0.x + b0.y*b0.y + b0.z*b0.z + b0.w*b0.w;
    float r1 = a1.x*a1.x + a1.y*a1.y + a1.z*a1.z + a1.w*a1.w
             + b1.x*b1.x + b1.y*b1.y + b1.z*b1.z + b1.w*b1.w;

    #pragma unroll
    for (int off = 1; off < 64; off <<= 1) {
        r0 += __shfl_xor(r0, off, 64);
        r1 += __shfl_xor(r1, off, 64);
    }
    if (lane == 0) {
        s_part[wave] = r0 + r1;
        m_part[wave] = fmaxf(r0, r1);
    }

    // padded atomic index: col c = lane*8+k -> c + (c>>3) = lane*9 + k
    const int base = lane * 9;
    #pragma unroll
    for (int k = 0; k < 8; ++k)
        atomicAdd(&colsum[base + k], col[k]);
    __syncthreads();

    float* o = ws + (size_t)blockIdx.x * NCOLS;
    if (t < NCOLS) o[t] = colsum[t + (t >> 3)];
    if (t == 0) {
        float s = 0.f, m = 0.f;
        #pragma unroll
        for (int k = 0; k < 16; ++k) {
            s += s_part[k];
            m  = fmaxf(m, m_part[k]);
        }
        ws[PS + blockIdx.x] = s;
        ws[PM + blockIdx.x] = m;
    }
}

// Block j: columns c = 8j..8j+7, fully summed over all 256 pass1 blocks.
// Thread t: c' = t&7, i = t>>3 (0..31); sums b = i*8+k, k=0..7.
// Then device-scope atomic accumulate; last block computes the scalar.
__global__ __launch_bounds__(256) void ndl_pass2(float* __restrict__ ws,
                                                 float* __restrict__ out) {
    __shared__ float wred[4 * 8];   // [wave][col'] per-wave column partials
    const int t    = threadIdx.x;
    const int lane = t & 63;
    const int wave = t >> 6;
    const int j    = blockIdx.x;
    const int c    = j * 8 + (t & 7);
    const int i    = t >> 3;

    const float* p = ws + (size_t)(i * 8) * NCOLS + c;
    float acc = 0.f;
    #pragma unroll
    for (int k = 0; k < 8; ++k)
        acc += p[(size_t)k * NCOLS];

    // sum over the 8 i-values within this wave (t bits 3,4,5)
    acc += __shfl_xor(acc, 8, 64);
    acc += __shfl_xor(acc, 16, 64);
    acc += __shfl_xor(acc, 32, 64);
    if (lane < 8) wred[wave * 8 + lane] = acc;
    __syncthreads();

    if (t < 8) {
        float cs = wred[t] + wred[8 + t] + wred[16 + t] + wred[24 + t];
        float q  = cs * cs;
        // sum the 8 squares (threads 0..7, same wave)
        q += __shfl_xor(q, 1, 64);
        q += __shfl_xor(q, 2, 64);
        q += __shfl_xor(q, 4, 64);
        if (t == 0) {
            float s = 0.f, m = 0.f;
            #pragma unroll
            for (int k = 0; k < 4; ++k) {
                s += ws[PS + j * 4 + k];
                m  = fmaxf(m, ws[PM + j * 4 + k]);
            }
            atomicAdd(&ws[PACC + 0], q);
            atomicAdd(&ws[PACC + 1], s);
            atomicMax((unsigned int*)&ws[PACC + 2], __float_as_uint(m)); // all >= 0
            __threadfence();
            unsigned int old = atomicAdd((unsigned int*)&ws[PACC + 3], 1u);
            if (old == NB2 - 1) {
                __threadfence();
                // read via atomic RMW -> coherent point (cross-XCD safe)
                float qv = atomicAdd(&ws[PACC + 0], 0.f);
                float sv = atomicAdd(&ws[PACC + 1], 0.f);
                float mv = __uint_as_float(
                    atomicMax((unsigned int*)&ws[PACC + 2], 0u));
                double numer = (double)NROWS * (double)sv - (double)qv;
                double count = (double)NROWS * ((double)NROWS - 1.0) * 0.5;
                out[0] = (float)(numer / (sqrt((double)mv) * count));
            }
        }
    }
}

extern "C" void kernel_launch(void* const* d_in, const int* in_sizes, int n_in,
                              void* d_out, int out_size, void* d_ws, size_t ws_size,
                              hipStream_t stream) {
    const float* x = (const float*)d_in[0];
    float* out = (float*)d_out;
    float* ws  = (float*)d_ws;

    ndl_pass1<<<NB1, 1024, 0, stream>>>(x, ws);
    ndl_pass2<<<NB2, 256, 0, stream>>>(ws, out);
}

// Round 2
// 67.608 us; speedup vs baseline: 1.1320x; 1.1320x over previous
//
#include <hip/hip_runtime.h>

// loss = (N*S - ||colsum||^2) / (sqrt(max_i sq_i) * N*(N-1)/2)
// where S = sum of all x^2, colsum[d] = sum_i x[i][d], sq_i = row squared norm.
// Derivation: sum_{i<j} (sq_i + sq_j - 2 x_i.x_j) = N*S - ||colsum||^2.
//
// 2-stage:
//   pass1 (256 blocks x 512 thr): 8 waves/block, wave handles 4 rows with
//         full register accumulation (col[8] per lane), then ONE pair of
//         conflict-free ds_write_b128 per lane into a per-wave LDS region
//         (no LDS atomics at all -- round-1 regression was 4x atomic traffic).
//         Cross-wave reduce: thread t sums 8 regions at col t -> ws partial.
//         Block 0 zeroes the 4 finisher slots (re-zeroed every launch =>
//         graph-replay safe; ws is poisoned between iterations).
//   pass2 (64 blocks x 256 thr): block j reduces cols [8j,8j+8) over the 256
//         partials -> q partial; also 4-wide slice of S/max partials; then
//         device-scope atomic accumulate + last-block-done finisher emits the
//         scalar.

#define NROWS 8192
#define NCOLS 512
#define NB1   256                 // pass1 block count
#define NB2   64                  // pass2 block count
#define PS    (NB1 * NCOLS)       // ws: S partials [NB1]
#define PM    (PS + NB1)          // ws: max partials [NB1]
#define PACC  (PM + NB1)          // ws: q_acc, s_acc, m_acc(uint), counter(uint)

__global__ __launch_bounds__(512) void ndl_pass1(const float* __restrict__ x,
                                                 float* __restrict__ ws) {
    __shared__ float wcol[8][NCOLS];   // 16 KB: per-wave column partials
    __shared__ float s_part[8];
    __shared__ float m_part[8];
    const int t    = threadIdx.x;
    const int lane = t & 63;
    const int wave = t >> 6;

    // finisher slots for pass2 (zeroed every launch -> graph-replay safe)
    if (blockIdx.x == 0 && t < 4) ws[PACC + t] = 0.f;

    // wave handles 4 consecutive rows; lane l covers columns 8l..8l+7
    const int row0 = blockIdx.x * 32 + wave * 4;
    const float4* xv = (const float4*)x;  // row stride = 128 float4

    float col[8] = {0.f, 0.f, 0.f, 0.f, 0.f, 0.f, 0.f, 0.f};
    float sp = 0.f;
    float maxsq = 0.f;

    #pragma unroll
    for (int r = 0; r < 4; ++r) {
        const int row = row0 + r;
        float4 a = xv[(size_t)row * 128 + lane * 2];
        float4 b = xv[(size_t)row * 128 + lane * 2 + 1];
        col[0] += a.x; col[1] += a.y; col[2] += a.z; col[3] += a.w;
        col[4] += b.x; col[5] += b.y; col[6] += b.z; col[7] += b.w;
        float rsq = a.x*a.x + a.y*a.y + a.z*a.z + a.w*a.w
                  + b.x*b.x + b.y*b.y + b.z*b.z + b.w*b.w;
        sp += rsq;
        #pragma unroll
        for (int off = 1; off < 64; off <<= 1)
            rsq += __shfl_xor(rsq, off, 64);
        maxsq = fmaxf(maxsq, rsq);
    }

    // one pair of conflict-free 16B LDS writes per lane (no atomics)
    float4* dst = (float4*)&wcol[wave][lane * 8];
    dst[0] = make_float4(col[0], col[1], col[2], col[3]);
    dst[1] = make_float4(col[4], col[5], col[6], col[7]);

    #pragma unroll
    for (int off = 1; off < 64; off <<= 1)
        sp += __shfl_xor(sp, off, 64);
    if (lane == 0) { s_part[wave] = sp; m_part[wave] = maxsq; }
    __syncthreads();

    // cross-wave reduce: thread t owns column t (bank t%32, 2-way = free)
    float cs = 0.f;
    #pragma unroll
    for (int w = 0; w < 8; ++w)
        cs += wcol[w][t];
    ws[(size_t)blockIdx.x * NCOLS + t] = cs;

    if (t == 0) {
        float s = 0.f, m = 0.f;
        #pragma unroll
        for (int k = 0; k < 8; ++k) {
            s += s_part[k];
            m  = fmaxf(m, m_part[k]);
        }
        ws[PS + blockIdx.x] = s;
        ws[PM + blockIdx.x] = m;
    }
}

// Block j: columns c = 8j..8j+7, fully summed over all 256 pass1 blocks.
// Thread t: c' = t&7, i = t>>3 (0..31); sums b = i*8+k, k=0..7.
// Then device-scope atomic accumulate; last block computes the scalar.
__global__ __launch_bounds__(256) void ndl_pass2(float* __restrict__ ws,
                                                 float* __restrict__ out) {
    __shared__ float wred[4 * 8];   // [wave][col'] per-wave column partials
    const int t    = threadIdx.x;
    const int lane = t & 63;
    const int wave = t >> 6;
    const int j    = blockIdx.x;
    const int c    = j * 8 + (t & 7);
    const int i    = t >> 3;

    const float* p = ws + (size_t)(i * 8) * NCOLS + c;
    float acc = 0.f;
    #pragma unroll
    for (int k = 0; k < 8; ++k)
        acc += p[(size_t)k * NCOLS];

    // sum over the 8 i-values within this wave (t bits 3,4,5)
    acc += __shfl_xor(acc, 8, 64);
    acc += __shfl_xor(acc, 16, 64);
    acc += __shfl_xor(acc, 32, 64);
    if (lane < 8) wred[wave * 8 + lane] = acc;
    __syncthreads();

    if (t < 8) {
        float cs = wred[t] + wred[8 + t] + wred[16 + t] + wred[24 + t];
        float q  = cs * cs;
        // sum the 8 squares (threads 0..7, same wave)
        q += __shfl_xor(q, 1, 64);
        q += __shfl_xor(q, 2, 64);
        q += __shfl_xor(q, 4, 64);
        if (t == 0) {
            float s = 0.f, m = 0.f;
            #pragma unroll
            for (int k = 0; k < 4; ++k) {
                s += ws[PS + j * 4 + k];
                m  = fmaxf(m, ws[PM + j * 4 + k]);
            }
            atomicAdd(&ws[PACC + 0], q);
            atomicAdd(&ws[PACC + 1], s);
            atomicMax((unsigned int*)&ws[PACC + 2], __float_as_uint(m)); // all >= 0
            __threadfence();
            unsigned int old = atomicAdd((unsigned int*)&ws[PACC + 3], 1u);
            if (old == NB2 - 1) {
                __threadfence();
                // read via atomic RMW -> coherent point (cross-XCD safe)
                float qv = atomicAdd(&ws[PACC + 0], 0.f);
                float sv = atomicAdd(&ws[PACC + 1], 0.f);
                float mv = __uint_as_float(
                    atomicMax((unsigned int*)&ws[PACC + 2], 0u));
                double numer = (double)NROWS * (double)sv - (double)qv;
                double count = (double)NROWS * ((double)NROWS - 1.0) * 0.5;
                out[0] = (float)(numer / (sqrt((double)mv) * count));
            }
        }
    }
}

extern "C" void kernel_launch(void* const* d_in, const int* in_sizes, int n_in,
                              void* d_out, int out_size, void* d_ws, size_t ws_size,
                              hipStream_t stream) {
    const float* x = (const float*)d_in[0];
    float* out = (float*)d_out;
    float* ws  = (float*)d_ws;

    ndl_pass1<<<NB1, 512, 0, stream>>>(x, ws);
    ndl_pass2<<<NB2, 256, 0, stream>>>(ws, out);
}